// Round 5
// baseline (528.607 us; speedup 1.0000x reference)
//
#include <hip/hip_runtime.h>

#define NCOLS 107
#define GROUP_F4 107          // 4 rows = 428 floats = 107 f4, 16B-aligned
#define THREADS 256
#define BN 4                  // f4-chunks per batch (4 d + 4 t = 8 loads)
#define GROUPS_PER_BLOCK 128  // 2 waves x 64 lanes cover 128 groups per range

typedef float f4 __attribute__((ext_vector_type(4)));

// ---- range/batch geometry ---------------------------------------------------
// R0 = chunks [0,54)  -> floats [0,216)   (rows 0,1 + row2 cols0..1)
// R1 = chunks [54,107)-> floats [216,428) (row2 cols2..106 + row3)
// Only split slice instance: slice0 of row2. head=float215 (R0), tail=216..223 (R1).
__device__ __host__ __forceinline__ constexpr int nbat(int cnt) {
    return (cnt + BN - 1) / BN;
}
__device__ __host__ __forceinline__ constexpr int blen(int b, int cnt) {
    return (BN * (b + 1) <= cnt) ? BN : (cnt - BN * b);
}

// ---- compile-time column classification -----------------------------------
// CAT slices: (1,10)(10,26)(27,34)(34,49)(49,55)(55,60)(60,62)(65,107)
// MSE cols: 0, 26, 62, 63, 64
__device__ __host__ __forceinline__ constexpr int slice_of(int col) {
    return (col >= 1  && col < 10) ? 0 :
           (col >= 10 && col < 26) ? 1 :
           (col >= 27 && col < 34) ? 2 :
           (col >= 34 && col < 49) ? 3 :
           (col >= 49 && col < 55) ? 4 :
           (col >= 55 && col < 60) ? 5 :
           (col >= 60 && col < 62) ? 6 :
           (col >= 65)             ? 7 : -1;   // -1 = MSE col
}
__device__ __host__ __forceinline__ constexpr int slice_last(int sid) {
    return sid == 0 ?  9 : sid == 1 ? 25 : sid == 2 ? 33 : sid == 3 ? 48 :
           sid == 4 ? 54 : sid == 5 ? 59 : sid == 6 ? 61 : 106;
}

// One element at group-float index L (0..427). All routing compile-time;
// s[sid] indexing static (rule #20). Head/tail of the split slice bypass the
// normal flush and go to hs/ts for the cross-wave combine.
template<int L>
__device__ __forceinline__ void elem(float d, float t, float (&s)[8],
                                     float& mse, float& dot, float& lse,
                                     float& hs, float& ts) {
    constexpr int col = L % NCOLS;
    constexpr int sid = slice_of(col);
    if constexpr (L == 215) {                       // head: row2 col1
        hs += __expf(d);
        dot = __builtin_fmaf(d, t, dot);
    } else if constexpr (L >= 216 && L <= 223) {    // tail: row2 cols2..9
        ts += __expf(d);
        dot = __builtin_fmaf(d, t, dot);
    } else if constexpr (sid < 0) {
        float df = d - t;
        mse += df * df;                             // MSE cols {0,26,62,63,64}
    } else {
        s[sid] += __expf(d);                        // slice sum for LSE
        dot = __builtin_fmaf(d, t, dot);            // one-hot: sum d*t
        if constexpr (col == slice_last(sid)) {
            lse += __logf(s[sid]);                  // slice complete -> flush
            s[sid] = 0.0f;
        }
    }
}

// ---- depth-3 software pipeline over one range [C0, C0+CNT) chunks ----------
template<int C0, int CNT, int B, int K = 0>
__device__ __forceinline__ void bload(const f4* __restrict__ gd,
                                      const f4* __restrict__ gt,
                                      f4 (&d)[BN], f4 (&t)[BN]) {
    if constexpr (K < blen(B, CNT)) {
        d[K] = gd[C0 + B * BN + K];                 // offsets fold into imm
        t[K] = gt[C0 + B * BN + K];
        bload<C0, CNT, B, K + 1>(gd, gt, d, t);
    }
}

template<int C0, int CNT, int B, int K = 0>
__device__ __forceinline__ void bproc(const f4 (&d)[BN], const f4 (&t)[BN],
                                      float (&s)[8], float& mse, float& dot,
                                      float& lse, float& hs, float& ts) {
    if constexpr (K < blen(B, CNT)) {
        constexpr int C = C0 + B * BN + K;
        elem<4 * C + 0>(d[K][0], t[K][0], s, mse, dot, lse, hs, ts);
        elem<4 * C + 1>(d[K][1], t[K][1], s, mse, dot, lse, hs, ts);
        elem<4 * C + 2>(d[K][2], t[K][2], s, mse, dot, lse, hs, ts);
        elem<4 * C + 3>(d[K][3], t[K][3], s, mse, dot, lse, hs, ts);
        bproc<C0, CNT, B, K + 1>(d, t, s, mse, dot, lse, hs, ts);
    }
}

template<int C0, int CNT, int B>
__device__ __forceinline__ void stage(const f4* __restrict__ gd,
                                      const f4* __restrict__ gt,
                                      f4 (&d0)[BN], f4 (&t0)[BN],
                                      f4 (&d1)[BN], f4 (&t1)[BN],
                                      f4 (&d2)[BN], f4 (&t2)[BN],
                                      float (&s)[8], float& mse, float& dot,
                                      float& lse, float& hs, float& ts) {
    f4 d3[BN], t3[BN];
    if constexpr (B + 3 < nbat(CNT)) {
        bload<C0, CNT, B + 3>(gd, gt, d3, t3);
        __builtin_amdgcn_sched_barrier(0);          // keep issue above compute
    }
    bproc<C0, CNT, B>(d0, t0, s, mse, dot, lse, hs, ts);
    if constexpr (B + 1 < nbat(CNT)) {
        stage<C0, CNT, B + 1>(gd, gt, d1, t1, d2, t2, d3, t3,
                              s, mse, dot, lse, hs, ts);
    }
}

template<int C0, int CNT>
__device__ __forceinline__ void run(const f4* __restrict__ gd,
                                    const f4* __restrict__ gt,
                                    float (&s)[8], float& mse, float& dot,
                                    float& lse, float& hs, float& ts) {
    f4 ad[BN], at[BN], bd[BN], bt[BN], cd[BN], ct[BN];
    bload<C0, CNT, 0>(gd, gt, ad, at);              // 3 batches in flight
    bload<C0, CNT, 1>(gd, gt, bd, bt);
    bload<C0, CNT, 2>(gd, gt, cd, ct);
    stage<C0, CNT, 0>(gd, gt, ad, at, bd, bt, cd, ct, s, mse, dot, lse, hs, ts);
}

// 4 waves/EU -> VGPR cap 128; grid 1024 blocks = 4 blocks/CU = 16 waves/CU.
__global__ __launch_bounds__(THREADS, 4) void multiloss_main(
        const float* __restrict__ dec, const float* __restrict__ tru,
        float2* __restrict__ ws) {
    __shared__ float headlds[GROUPS_PER_BLOCK];     // hs from R0 waves
    int lane = threadIdx.x & 63;
    int wid  = threadIdx.x >> 6;                    // 0..3
    int half = wid >> 1;                            // 0 -> R0, 1 -> R1 (wave-uniform)
    int gloc = (wid & 1) * 64 + lane;               // 0..127 within block
    int g    = blockIdx.x * GROUPS_PER_BLOCK + gloc;

    float mse = 0.0f, dot = 0.0f, lse = 0.0f, hs = 0.0f, ts = 0.0f;
    float s[8] = {0.0f, 0.0f, 0.0f, 0.0f, 0.0f, 0.0f, 0.0f, 0.0f};
    const f4* gd = (const f4*)dec + (size_t)g * GROUP_F4;   // byte off g*1712
    const f4* gt = (const f4*)tru + (size_t)g * GROUP_F4;

    if (half == 0) {
        run<0, 54>(gd, gt, s, mse, dot, lse, hs, ts);       // floats [0,216)
        headlds[gloc] = hs;
    } else {
        run<54, 53>(gd, gt, s, mse, dot, lse, hs, ts);      // floats [216,428)
    }
    __syncthreads();
    if (half == 1)
        lse += __logf(headlds[gloc] + ts);          // stitch split slice0(row2)

    float ce = lse - dot;
    // 64-lane shuffle reduction; one ws slot per wave, no atomics
#pragma unroll
    for (int off = 32; off > 0; off >>= 1) {
        mse += __shfl_down(mse, off, 64);
        ce  += __shfl_down(ce,  off, 64);
    }
    if (lane == 0)
        ws[blockIdx.x * 4 + wid] = make_float2(mse, ce);
}

__global__ __launch_bounds__(256) void multiloss_fin(
        const float2* __restrict__ ws, float* __restrict__ out,
        int nslots, float invN) {
    float m = 0.0f, c = 0.0f;
    for (int i = threadIdx.x; i < nslots; i += 256) {
        float2 v = ws[i];
        m += v.x; c += v.y;
    }
#pragma unroll
    for (int off = 32; off > 0; off >>= 1) {
        m += __shfl_down(m, off, 64);
        c += __shfl_down(c, off, 64);
    }
    __shared__ float sm[4], sc[4];
    int wid  = threadIdx.x >> 6;
    int lane = threadIdx.x & 63;
    if (lane == 0) { sm[wid] = m; sc[wid] = c; }
    __syncthreads();
    if (threadIdx.x == 0) {
        float mse = (sm[0] + sm[1] + sm[2] + sm[3]) * invN;
        float ce  = (sc[0] + sc[1] + sc[2] + sc[3]) * invN;
        out[0] = mse + ce;
        out[1] = mse;
        out[2] = ce;
    }
}

extern "C" void kernel_launch(void* const* d_in, const int* in_sizes, int n_in,
                              void* d_out, int out_size, void* d_ws, size_t ws_size,
                              hipStream_t stream) {
    const float* dec = (const float*)d_in[0];
    const float* tru = (const float*)d_in[1];
    int nrows   = in_sizes[0] / NCOLS;                  // 524288
    int ngroups = nrows / 4;                            // 131072
    int nblocks = ngroups / GROUPS_PER_BLOCK;           // 1024 (exact)
    int nwaves  = nblocks * 4;                          // 4096 slots, 32 KB ws
    float2* ws = (float2*)d_ws;
    multiloss_main<<<nblocks, THREADS, 0, stream>>>(dec, tru, ws);
    multiloss_fin<<<1, 256, 0, stream>>>(ws, (float*)d_out, nwaves,
                                         1.0f / (float)nrows);
}

// Round 6
// 478.017 us; speedup vs baseline: 1.1058x; 1.1058x over previous
//
#include <hip/hip_runtime.h>

#define NCOLS 107
#define GROUP_F4 107          // 4 rows = 428 floats = 107 f4, 16B-aligned
#define THREADS 256
#define BN 3                  // f4-chunks per batch (3 d + 3 t = 6 loads)
#define GROUPS_PER_BLOCK 128  // 2 waves x 64 lanes cover 128 groups per range

typedef float f4 __attribute__((ext_vector_type(4)));

// ---- range/batch geometry ---------------------------------------------------
// Split at chunk 56 (= float 224 = row2 col10 = start of slice 1): BOTH a 16B
// boundary and a slice boundary, so each range holds only complete slice
// instances. R0 = chunks [0,56): rows 0,1 + row2 cols0..9 (MSE col0 + slice0).
// R1 = chunks [56,107): row2 cols10..106 + row3. No stitch, no LDS, no sync.
__device__ __host__ __forceinline__ constexpr int nbat(int cnt) {
    return (cnt + BN - 1) / BN;
}
__device__ __host__ __forceinline__ constexpr int blen(int b, int cnt) {
    return (BN * (b + 1) <= cnt) ? BN : (cnt - BN * b);
}

// ---- compile-time column classification -----------------------------------
// CAT slices: (1,10)(10,26)(27,34)(34,49)(49,55)(55,60)(60,62)(65,107)
// MSE cols: 0, 26, 62, 63, 64
__device__ __host__ __forceinline__ constexpr int slice_of(int col) {
    return (col >= 1  && col < 10) ? 0 :
           (col >= 10 && col < 26) ? 1 :
           (col >= 27 && col < 34) ? 2 :
           (col >= 34 && col < 49) ? 3 :
           (col >= 49 && col < 55) ? 4 :
           (col >= 55 && col < 60) ? 5 :
           (col >= 60 && col < 62) ? 6 :
           (col >= 65)             ? 7 : -1;   // -1 = MSE col
}
__device__ __host__ __forceinline__ constexpr int slice_last(int sid) {
    return sid == 0 ?  9 : sid == 1 ? 25 : sid == 2 ? 33 : sid == 3 ? 48 :
           sid == 4 ? 54 : sid == 5 ? 59 : sid == 6 ? 61 : 106;
}

// One element at group-float index L (0..427). col/sid/flush all compile-time;
// s[sid] indexing static (rule #20: no scratch). Identical for both ranges.
template<int L>
__device__ __forceinline__ void elem(float d, float t, float (&s)[8],
                                     float& mse, float& dot, float& lse) {
    constexpr int col = L % NCOLS;
    constexpr int sid = slice_of(col);
    if constexpr (sid < 0) {
        float df = d - t;
        mse += df * df;                       // MSE cols {0,26,62,63,64}
    } else {
        s[sid] += __expf(d);                  // slice sum for LSE
        dot = __builtin_fmaf(d, t, dot);      // one-hot: sum d*t = logit[label]
        if constexpr (col == slice_last(sid)) {
            lse += __logf(s[sid]);            // slice complete -> flush
            s[sid] = 0.0f;
        }
    }
}

// ---- depth-2 software pipeline over one range [C0, C0+CNT) chunks ----------
// Round-5 post-mortem: depth-3 + dual instantiation blew the 128-VGPR cap and
// spilled (VGPR=64, 75 MB scratch writes). Depth-2 with BN=3 needs ~100 VGPR:
// ~30 regs of allocator slack under the cap.
template<int C0, int CNT, int B, int K = 0>
__device__ __forceinline__ void bload(const f4* __restrict__ gd,
                                      const f4* __restrict__ gt,
                                      f4 (&d)[BN], f4 (&t)[BN]) {
    if constexpr (K < blen(B, CNT)) {
        d[K] = gd[C0 + B * BN + K];           // offsets fold into imm
        t[K] = gt[C0 + B * BN + K];
        bload<C0, CNT, B, K + 1>(gd, gt, d, t);
    }
}

template<int C0, int CNT, int B, int K = 0>
__device__ __forceinline__ void bproc(const f4 (&d)[BN], const f4 (&t)[BN],
                                      float (&s)[8],
                                      float& mse, float& dot, float& lse) {
    if constexpr (K < blen(B, CNT)) {
        constexpr int C = C0 + B * BN + K;
        elem<4 * C + 0>(d[K][0], t[K][0], s, mse, dot, lse);
        elem<4 * C + 1>(d[K][1], t[K][1], s, mse, dot, lse);
        elem<4 * C + 2>(d[K][2], t[K][2], s, mse, dot, lse);
        elem<4 * C + 3>(d[K][3], t[K][3], s, mse, dot, lse);
        bproc<C0, CNT, B, K + 1>(d, t, s, mse, dot, lse);
    }
}

// stage<B>: d0/t0 = batch B (process now); d1/t1 = B+1 in flight.
// Issue B+2, fence scheduler, process B, rotate.
template<int C0, int CNT, int B>
__device__ __forceinline__ void stage(const f4* __restrict__ gd,
                                      const f4* __restrict__ gt,
                                      f4 (&d0)[BN], f4 (&t0)[BN],
                                      f4 (&d1)[BN], f4 (&t1)[BN],
                                      float (&s)[8],
                                      float& mse, float& dot, float& lse) {
    f4 d2[BN], t2[BN];
    if constexpr (B + 2 < nbat(CNT)) {
        bload<C0, CNT, B + 2>(gd, gt, d2, t2);
        __builtin_amdgcn_sched_barrier(0);    // keep issue above compute
    }
    bproc<C0, CNT, B>(d0, t0, s, mse, dot, lse);
    if constexpr (B + 1 < nbat(CNT)) {
        stage<C0, CNT, B + 1>(gd, gt, d1, t1, d2, t2, s, mse, dot, lse);
    }
}

template<int C0, int CNT>
__device__ __forceinline__ void run(const f4* __restrict__ gd,
                                    const f4* __restrict__ gt,
                                    float (&s)[8],
                                    float& mse, float& dot, float& lse) {
    f4 ad[BN], at[BN], bd[BN], bt[BN];
    bload<C0, CNT, 0>(gd, gt, ad, at);        // 2 batches in flight
    bload<C0, CNT, 1>(gd, gt, bd, bt);
    stage<C0, CNT, 0>(gd, gt, ad, at, bd, bt, s, mse, dot, lse);
}

// 4 waves/EU -> VGPR cap 128; grid 1024 blocks = 4 blocks/CU = 16 waves/CU.
__global__ __launch_bounds__(THREADS, 4) void multiloss_main(
        const float* __restrict__ dec, const float* __restrict__ tru,
        float2* __restrict__ ws) {
    int lane = threadIdx.x & 63;
    int wid  = threadIdx.x >> 6;              // 0..3
    int half = wid >> 1;                      // 0 -> R0, 1 -> R1 (wave-uniform)
    int gloc = (wid & 1) * 64 + lane;         // 0..127 within block
    int g    = blockIdx.x * GROUPS_PER_BLOCK + gloc;

    float mse = 0.0f, dot = 0.0f, lse = 0.0f;
    float s[8] = {0.0f, 0.0f, 0.0f, 0.0f, 0.0f, 0.0f, 0.0f, 0.0f};
    const f4* gd = (const f4*)dec + (size_t)g * GROUP_F4;   // byte off g*1712
    const f4* gt = (const f4*)tru + (size_t)g * GROUP_F4;

    if (half == 0) {
        run<0, 56>(gd, gt, s, mse, dot, lse); // floats [0,224)
    } else {
        run<56, 51>(gd, gt, s, mse, dot, lse);// floats [224,428)
    }

    float ce = lse - dot;
    // 64-lane shuffle reduction; one ws slot per wave, no atomics
#pragma unroll
    for (int off = 32; off > 0; off >>= 1) {
        mse += __shfl_down(mse, off, 64);
        ce  += __shfl_down(ce,  off, 64);
    }
    if (lane == 0)
        ws[blockIdx.x * 4 + wid] = make_float2(mse, ce);
}

__global__ __launch_bounds__(256) void multiloss_fin(
        const float2* __restrict__ ws, float* __restrict__ out,
        int nslots, float invN) {
    float m = 0.0f, c = 0.0f;
    for (int i = threadIdx.x; i < nslots; i += 256) {
        float2 v = ws[i];
        m += v.x; c += v.y;
    }
#pragma unroll
    for (int off = 32; off > 0; off >>= 1) {
        m += __shfl_down(m, off, 64);
        c += __shfl_down(c, off, 64);
    }
    __shared__ float sm[4], sc[4];
    int wid  = threadIdx.x >> 6;
    int lane = threadIdx.x & 63;
    if (lane == 0) { sm[wid] = m; sc[wid] = c; }
    __syncthreads();
    if (threadIdx.x == 0) {
        float mse = (sm[0] + sm[1] + sm[2] + sm[3]) * invN;
        float ce  = (sc[0] + sc[1] + sc[2] + sc[3]) * invN;
        out[0] = mse + ce;
        out[1] = mse;
        out[2] = ce;
    }
}

extern "C" void kernel_launch(void* const* d_in, const int* in_sizes, int n_in,
                              void* d_out, int out_size, void* d_ws, size_t ws_size,
                              hipStream_t stream) {
    const float* dec = (const float*)d_in[0];
    const float* tru = (const float*)d_in[1];
    int nrows   = in_sizes[0] / NCOLS;                  // 524288
    int ngroups = nrows / 4;                            // 131072
    int nblocks = ngroups / GROUPS_PER_BLOCK;           // 1024 (exact)
    int nwaves  = nblocks * 4;                          // 4096 slots, 32 KB ws
    float2* ws = (float2*)d_ws;
    multiloss_main<<<nblocks, THREADS, 0, stream>>>(dec, tru, ws);
    multiloss_fin<<<1, 256, 0, stream>>>(ws, (float*)d_out, nwaves,
                                         1.0f / (float)nrows);
}

// Round 7
// 441.002 us; speedup vs baseline: 1.1986x; 1.0839x over previous
//
#include <hip/hip_runtime.h>

#define NCOLS 107
#define ROWS_PER_TILE 16
#define TILE_FLOATS (ROWS_PER_TILE * NCOLS)   // 1712 floats (6848 B, 16B-aligned)
#define TILE_VEC (TILE_FLOATS / 4)            // 428 f4 per tile per array
#define THREADS 256
#define WAVES_PER_BLOCK 4
#define BLOCKS 1280                           // 5 blocks/CU resident (27.4 KB LDS)
#define NWAVES (BLOCKS * WAVES_PER_BLOCK)     // 5120 persistent waves

typedef float f4 __attribute__((ext_vector_type(4)));

// inputs ~N(0,1): exp can't overflow fp32 (absmax=0.0 verified R5/R6)
template<int S, int E>
__device__ __forceinline__ float slice_lse(const float* dr) {
    constexpr int L = E - S;
    float s = 0.0f;
#pragma unroll
    for (int j = 0; j < L; ++j) s += __expf(dr[S + j]);
    return __logf(s);
}

// order-free pass over one f4 held in registers. idx = tile-LOCAL f4 index
// (tile start ≡ 0 mod 107 since 1712 = 16*107, so local idx determines col).
__device__ __forceinline__ void lin4(int idx, f4 dv, f4 tv, bool valid,
                                     float& mse, float& dot) {
    unsigned c4  = (unsigned)idx * 4u;
    unsigned row = c4 / NCOLS;                 // magic-mul div
    unsigned col = c4 - row * NCOLS;
#pragma unroll
    for (int k = 0; k < 4; ++k) {
        float d = dv[k], tt = tv[k];
        bool ismse = (col == 0) | (col == 26) | ((unsigned)(col - 62) <= 2u);
        float df = d - tt;
        mse += (valid && ismse)  ? df * df : 0.0f;   // MSE cols {0,26,62,63,64}
        dot += (valid && !ismse) ? d * tt  : 0.0f;   // one-hot: Σd·t = Σ logit[label]
        ++col; if (col >= NCOLS) col = 0;
    }
}

__global__ __launch_bounds__(THREADS) void multiloss_main(
        const float* __restrict__ dec, const float* __restrict__ tru,
        float2* __restrict__ ws, int ntiles) {
    // Wave-private staging: NO __syncthreads in this kernel. In-order DS pipe
    // + wave lockstep give cross-lane visibility; waves drift freely in phase.
    __shared__ float sdec[WAVES_PER_BLOCK * TILE_FLOATS];  // 27392 B
    int lane  = threadIdx.x & 63;
    float* buf = sdec + (threadIdx.x >> 6) * TILE_FLOATS;
    f4* b4 = (f4*)buf;
    int gwave = (blockIdx.x * THREADS + threadIdx.x) >> 6;

    // ragged last f4 slot: 428 = 6*64 + 44. Lanes >=44 clamp to slot 427:
    // duplicate load + same-value same-address ds_write (benign), compute masked.
    bool v6 = lane < (TILE_VEC - 384);
    int  i6 = v6 ? (384 + lane) : (TILE_VEC - 1);

    float mse = 0.0f, dot = 0.0f, lse = 0.0f;

    int tile = gwave;                          // gwave < 5120 <= ntiles always
    {   // prologue: batch-issue ALL 14 loads of the first tile (MLP!)
        const f4* gd = (const f4*)dec + (size_t)tile * TILE_VEC;
        const f4* gt = (const f4*)tru + (size_t)tile * TILE_VEC;
        // fallthrough into loop with registers pending
        f4 d0 = gd[lane], d1 = gd[64+lane], d2 = gd[128+lane], d3 = gd[192+lane],
           d4 = gd[256+lane], d5 = gd[320+lane], d6 = gd[i6];
        f4 t0 = gt[lane], t1 = gt[64+lane], t2 = gt[128+lane], t3 = gt[192+lane],
           t4 = gt[256+lane], t5 = gt[320+lane], t6 = gt[i6];

        while (tile < ntiles) {
            // ---- stage dec tile to LDS: ONE vmcnt wait, then 7 ds_write_b128
            // (consecutive lanes -> consecutive 16B: 2-way bank alias = free)
            b4[lane] = d0; b4[64+lane] = d1; b4[128+lane] = d2;
            b4[192+lane] = d3; b4[256+lane] = d4; b4[320+lane] = d5;
            b4[i6] = d6;
            // ---- linear pass from registers (frees d*/t* for prefetch)
            lin4(lane,     d0, t0, true, mse, dot);
            lin4(64+lane,  d1, t1, true, mse, dot);
            lin4(128+lane, d2, t2, true, mse, dot);
            lin4(192+lane, d3, t3, true, mse, dot);
            lin4(256+lane, d4, t4, true, mse, dot);
            lin4(320+lane, d5, t5, true, mse, dot);
            lin4(i6,       d6, t6, v6,   mse, dot);
            // ---- prefetch next tile NOW: 14 loads in flight across the whole
            // lse phase and the next iteration's single vmcnt wait.
            int nt = tile + NWAVES;            // wave-uniform branch
            if (nt < ntiles) {
                const f4* ngd = (const f4*)dec + (size_t)nt * TILE_VEC;
                const f4* ngt = (const f4*)tru + (size_t)nt * TILE_VEC;
                d0 = ngd[lane]; d1 = ngd[64+lane]; d2 = ngd[128+lane];
                d3 = ngd[192+lane]; d4 = ngd[256+lane]; d5 = ngd[320+lane];
                d6 = ngd[i6];
                t0 = ngt[lane]; t1 = ngt[64+lane]; t2 = ngt[128+lane];
                t3 = ngt[192+lane]; t4 = ngt[256+lane]; t5 = ngt[320+lane];
                t6 = ngt[i6];
            }
            // ---- per-row lse from wave-private LDS (no barrier). Next
            // iteration's ds_writes are ordered after these reads by the
            // in-order per-wave DS pipe, so no WAR hazard.
            int row  = lane & 15;
            int part = lane >> 4;
            const float* dr = buf + row * NCOLS;
            if (part == 0) {
                lse += slice_lse<65, 107>(dr);
            } else if (part == 1) {
                lse += slice_lse<10, 26>(dr) + slice_lse<34, 49>(dr);
            } else if (part == 2) {
                lse += slice_lse<1, 10>(dr) + slice_lse<27, 34>(dr)
                     + slice_lse<49, 55>(dr);
            } else {
                lse += slice_lse<55, 60>(dr) + slice_lse<60, 62>(dr);
            }
            tile = nt;
        }
    }

    float ce = lse - dot;
    // wave (64-lane) shuffle reduction; one ws slot per wave, no atomics
#pragma unroll
    for (int off = 32; off > 0; off >>= 1) {
        mse += __shfl_down(mse, off, 64);
        ce  += __shfl_down(ce,  off, 64);
    }
    if (lane == 0)
        ws[gwave] = make_float2(mse, ce);
}

__global__ __launch_bounds__(256) void multiloss_fin(
        const float2* __restrict__ ws, float* __restrict__ out,
        int nslots, float invN) {
    float m = 0.0f, c = 0.0f;
    for (int i = threadIdx.x; i < nslots; i += 256) {
        float2 v = ws[i];
        m += v.x; c += v.y;
    }
#pragma unroll
    for (int off = 32; off > 0; off >>= 1) {
        m += __shfl_down(m, off, 64);
        c += __shfl_down(c, off, 64);
    }
    __shared__ float sm[4], sc[4];
    int wid  = threadIdx.x >> 6;
    int lane = threadIdx.x & 63;
    if (lane == 0) { sm[wid] = m; sc[wid] = c; }
    __syncthreads();
    if (threadIdx.x == 0) {
        float mse = (sm[0] + sm[1] + sm[2] + sm[3]) * invN;
        float ce  = (sc[0] + sc[1] + sc[2] + sc[3]) * invN;
        out[0] = mse + ce;
        out[1] = mse;
        out[2] = ce;
    }
}

extern "C" void kernel_launch(void* const* d_in, const int* in_sizes, int n_in,
                              void* d_out, int out_size, void* d_ws, size_t ws_size,
                              hipStream_t stream) {
    const float* dec = (const float*)d_in[0];
    const float* tru = (const float*)d_in[1];
    int nrows  = in_sizes[0] / NCOLS;
    int ntiles = nrows / ROWS_PER_TILE;        // 32768 exact at BATCH=524288
    float2* ws = (float2*)d_ws;                // NWAVES*8 B = 40 KB
    multiloss_main<<<BLOCKS, THREADS, 0, stream>>>(dec, tru, ws, ntiles);
    multiloss_fin<<<1, 256, 0, stream>>>(ws, (float*)d_out, NWAVES,
                                         1.0f / (float)nrows);
}